// Round 4
// baseline (1325.405 us; speedup 1.0000x reference)
//
#include <hip/hip_runtime.h>
#include <cmath>

// Problem constants
#define CN   256   // channels (N_DIST)
#define HN   256   // H
#define WN   192   // W
#define KN   129   // kernel taps
#define RN   64    // radius
#define SN   256   // padded size
#define PADN 32    // (SN - WN)/2

// ================= conv along W (last axis), LDS-tiled =================
// Block: 256 thr = 4 waves. Tile: 64 rows x 64 output cols; lane = row.
// LDS window pitch 196 words (16B-aligned rows; banks spread uniformly).
// Window refill: one ds_read_b128 per 4 taps, consumed ~14 taps later.
// Coefficients in LDS (in-order lgkm), float4-prefetched one chunk ahead.
template <int WD, bool ACC>
__global__ __launch_bounds__(256) void conv_w_lds(const float* __restrict__ in,
                                                  const float* __restrict__ kern,
                                                  float* __restrict__ out) {
    constexpr int PITCH = 196;
    __shared__ float lds[64 * PITCH + 132];
    float* __restrict__ ldsK = lds + 64 * PITCH;
    const int tid = threadIdx.x;
    const int x0  = blockIdx.x * 64;
    const int h0  = blockIdx.y * 64;
    const int c   = blockIdx.z;
    const float* __restrict__ in_c = in + ((size_t)c * HN + h0) * WD;

    // stage 64 rows x 192 window cols (global cols x0-64 .. x0+127), zeros outside
    for (int idx = tid; idx < 64 * 192; idx += 256) {
        int r = idx / 192, col = idx - r * 192;
        int g = x0 + col - 64;
        lds[r * PITCH + col] = (g >= 0 && g < WD) ? in_c[(size_t)r * WD + g] : 0.f;
    }
    if (tid < 132) ldsK[tid] = (tid < KN) ? kern[c * KN + tid] : 0.f;
    __syncthreads();

    const int wv = tid >> 6;        // wave 0..3 -> output col chunk
    const int l  = tid & 63;        // lane = row
    const int base = l * PITCH + wv * 16;          // window element 0 (16B aligned)
    const float4* __restrict__ win4 = (const float4*)(lds + base);
    const float4* __restrict__ k4   = (const float4*)ldsK;

    float w[32], acc[16], kc[16];
#pragma unroll
    for (int i = 0; i < 8; ++i) {
        float4 v = win4[i];
        w[4*i] = v.x; w[4*i+1] = v.y; w[4*i+2] = v.z; w[4*i+3] = v.w;
    }
#pragma unroll
    for (int t = 0; t < 16; ++t) acc[t] = 0.f;
#pragma unroll
    for (int q = 0; q < 4; ++q) {
        float4 kv = k4[q];
        kc[4*q] = kv.x; kc[4*q+1] = kv.y; kc[4*q+2] = kv.z; kc[4*q+3] = kv.w;
    }

#pragma unroll
    for (int ch = 0; ch < 8; ++ch) {
        float kn[16];
        if (ch < 7) {
#pragma unroll
            for (int q = 0; q < 4; ++q) {
                float4 kv = k4[(ch + 1) * 4 + q];
                kn[4*q] = kv.x; kn[4*q+1] = kv.y; kn[4*q+2] = kv.z; kn[4*q+3] = kv.w;
            }
        }
#pragma unroll
        for (int s = 0; s < 4; ++s) {
            const int j = ch * 16 + s * 4;
#pragma unroll
            for (int u = 0; u < 4; ++u) {
                const float kj = kc[s * 4 + u];
#pragma unroll
                for (int t = 0; t < 16; ++t)
                    acc[t] = fmaf(w[(j + u + t) & 31], kj, acc[t]);
            }
            if (ch < 7) {          // refill elements j+32..j+35 into slots (j&31)..+3
                float4 v = win4[j / 4 + 8];
                const int sl = j & 31;
                w[sl] = v.x; w[sl+1] = v.y; w[sl+2] = v.z; w[sl+3] = v.w;
            }
        }
        if (ch < 7) {
#pragma unroll
            for (int i = 0; i < 16; ++i) kc[i] = kn[i];
        }
    }
    {   // final tap j = 128: elements 128..143 live in slots 0..15
        const float k128 = ldsK[128];
#pragma unroll
        for (int t = 0; t < 16; ++t) acc[t] = fmaf(w[t], k128, acc[t]);
    }

    float4* __restrict__ o4 =
        (float4*)(out + ((size_t)c * HN + h0 + l) * WD + x0 + wv * 16);
#pragma unroll
    for (int q = 0; q < 4; ++q) {
        float4 v;
        v.x = acc[4*q]; v.y = acc[4*q+1]; v.z = acc[4*q+2]; v.w = acc[4*q+3];
        if (ACC) {
            float4 o = o4[q];
            v.x += o.x; v.y += o.y; v.z += o.z; v.w += o.w;
        }
        o4[q] = v;
    }
}

// ================= conv along H (axis 1), LDS-tiled =================
// Block: 256 thr = 4 waves. Tile: 64 output rows x 64 cols; lane = col.
// Row-major pitch 64 (conflict-free). Refills: 4x b32 every 4 taps,
// consumed ~14 taps later.
__global__ __launch_bounds__(256) void conv_h_lds(const float* __restrict__ in,
                                                  const float* __restrict__ kern,
                                                  float* __restrict__ out) {
    __shared__ float lds[192 * 64 + 132];
    float* __restrict__ ldsK = lds + 192 * 64;
    const int tid = threadIdx.x;
    const int x0  = blockIdx.x * 64;
    const int h0  = blockIdx.y * 64;
    const int c   = blockIdx.z;
    const float* __restrict__ in_c = in + (size_t)c * HN * WN;

    // stage rows h0-64 .. h0+127 x 64 cols, zeros outside [0,HN)
    for (int idx = tid; idx < 192 * 64; idx += 256) {
        int r = idx >> 6, col = idx & 63;
        int g = h0 + r - 64;
        lds[r * 64 + col] = (g >= 0 && g < HN) ? in_c[(size_t)g * WN + x0 + col] : 0.f;
    }
    if (tid < 132) ldsK[tid] = (tid < KN) ? kern[c * KN + tid] : 0.f;
    __syncthreads();

    const int wv = tid >> 6;        // wave -> output row chunk
    const int l  = tid & 63;        // lane = col
    const int baseRow = wv * 16;    // window element i = lds[(baseRow+i)*64 + l]
    const float4* __restrict__ k4 = (const float4*)ldsK;

    float w[32], acc[16], kc[16];
#pragma unroll
    for (int i = 0; i < 32; ++i) w[i] = lds[(baseRow + i) * 64 + l];
#pragma unroll
    for (int t = 0; t < 16; ++t) acc[t] = 0.f;
#pragma unroll
    for (int q = 0; q < 4; ++q) {
        float4 kv = k4[q];
        kc[4*q] = kv.x; kc[4*q+1] = kv.y; kc[4*q+2] = kv.z; kc[4*q+3] = kv.w;
    }

#pragma unroll
    for (int ch = 0; ch < 8; ++ch) {
        float kn[16];
        if (ch < 7) {
#pragma unroll
            for (int q = 0; q < 4; ++q) {
                float4 kv = k4[(ch + 1) * 4 + q];
                kn[4*q] = kv.x; kn[4*q+1] = kv.y; kn[4*q+2] = kv.z; kn[4*q+3] = kv.w;
            }
        }
#pragma unroll
        for (int s = 0; s < 4; ++s) {
            const int j = ch * 16 + s * 4;
#pragma unroll
            for (int u = 0; u < 4; ++u) {
                const float kj = kc[s * 4 + u];
#pragma unroll
                for (int t = 0; t < 16; ++t)
                    acc[t] = fmaf(w[(j + u + t) & 31], kj, acc[t]);
            }
            if (ch < 7) {          // refill elements j+32..j+35
                const int sl = j & 31;
#pragma unroll
                for (int q = 0; q < 4; ++q)
                    w[sl + q] = lds[(baseRow + j + 32 + q) * 64 + l];
            }
        }
        if (ch < 7) {
#pragma unroll
            for (int i = 0; i < 16; ++i) kc[i] = kn[i];
        }
    }
    {
        const float k128 = ldsK[128];
#pragma unroll
        for (int t = 0; t < 16; ++t) acc[t] = fmaf(w[t], k128, acc[t]);
    }

    float* __restrict__ ob = out + ((size_t)c * HN + h0 + wv * 16) * WN + x0 + l;
#pragma unroll
    for (int t = 0; t < 16; ++t) ob[(size_t)t * WN] = acc[t];
}

// ---------------- forward rotate of implicitly-padded C ----------------
// 4 outputs per thread along j (spaced 32) -> 16 gathers in flight.
__global__ __launch_bounds__(256) void rot_fwd_k(const float* __restrict__ Cin,
                                                 float* __restrict__ out,
                                                 float ca, float sa) {
    const int jb = blockIdx.x * 128 + threadIdx.x;  // + q*32
    const int i  = blockIdx.y * 8 + threadIdx.y;    // 0..255
    const int c  = blockIdx.z;
    const float cc = (SN - 1) * 0.5f;               // 127.5
    const float yy = (float)i - cc;
    const float* __restrict__ base = Cin + (size_t)c * HN * WN;
    float* __restrict__ orow = out + ((size_t)c * SN + i) * SN;
#pragma unroll
    for (int q = 0; q < 4; ++q) {
        const int j = jb + q * 32;
        float xx = (float)j - cc;
        float sy = ca * yy + sa * xx + cc;
        float sx = -sa * yy + ca * xx + cc;
        float y0f = floorf(sy), x0f = floorf(sx);
        float fy = sy - y0f, fx = sx - x0f;
        int y0 = (int)y0f, x0 = (int)x0f;
        auto g = [&](int yi, int xi) -> float {
            int p = xi - PADN;
            return (yi >= 0 && yi < SN && p >= 0 && p < WN)
                       ? base[(size_t)yi * WN + p] : 0.f;
        };
        float v = g(y0, x0) * (1.f - fy) * (1.f - fx)
                + g(y0, x0 + 1) * (1.f - fy) * fx
                + g(y0 + 1, x0) * fy * (1.f - fx)
                + g(y0 + 1, x0 + 1) * fy * fx;
        orow[j] = v;
    }
}

// ---------------- inverse rotate + accumulate into cropped acc -------------
// 2 outputs per thread along xc (spaced 32) -> 8 gathers in flight.
__global__ __launch_bounds__(256) void rot_bwd_k(const float* __restrict__ U,
                                                 float* __restrict__ acc,
                                                 float ca, float sa) {
    const int xb = blockIdx.x * 64 + threadIdx.x;  // + q*32
    const int i  = blockIdx.y * 8 + threadIdx.y;   // 0..255
    const int c  = blockIdx.z;
    const float cc = (SN - 1) * 0.5f;
    const float yy = (float)i - cc;
    const float* __restrict__ base = U + (size_t)c * SN * SN;
    float* __restrict__ arow = acc + ((size_t)c * HN + i) * WN;
#pragma unroll
    for (int q = 0; q < 2; ++q) {
        const int xc = xb + q * 32;
        const int j  = xc + PADN;
        float xx = (float)j - cc;
        float sy = ca * yy + sa * xx + cc;
        float sx = -sa * yy + ca * xx + cc;
        float y0f = floorf(sy), x0f = floorf(sx);
        float fy = sy - y0f, fx = sx - x0f;
        int y0 = (int)y0f, x0 = (int)x0f;
        auto g = [&](int yi, int xi) -> float {
            return (yi >= 0 && yi < SN && xi >= 0 && xi < SN)
                       ? base[(size_t)yi * SN + xi] : 0.f;
        };
        float v = g(y0, x0) * (1.f - fy) * (1.f - fx)
                + g(y0, x0 + 1) * (1.f - fy) * fx
                + g(y0 + 1, x0) * fy * (1.f - fx)
                + g(y0 + 1, x0 + 1) * fy * fx;
        arow[xc] += v;
    }
}

// ---------------- finalize: out = (C + acc) / norm[c], float4 ----------------
__global__ __launch_bounds__(256) void final_k(float* __restrict__ outC,
                                               const float* __restrict__ acc,
                                               const float* __restrict__ norm) {
    size_t i4 = (size_t)blockIdx.x * 256 + threadIdx.x;
    int c = (int)(i4 / (HN * WN / 4));
    float4* o4 = (float4*)outC;
    const float4* a4 = (const float4*)acc;
    float inv = 1.f / norm[c];
    float4 o = o4[i4], a = a4[i4];
    o.x = (o.x + a.x) * inv; o.y = (o.y + a.y) * inv;
    o.z = (o.z + a.z) * inv; o.w = (o.w + a.w) * inv;
    o4[i4] = o;
}

extern "C" void kernel_launch(void* const* d_in, const int* in_sizes, int n_in,
                              void* d_out, int out_size, void* d_ws, size_t ws_size,
                              hipStream_t stream) {
    const float* x    = (const float*)d_in[0];
    const float* kg   = (const float*)d_in[1];
    const float* kw   = (const float*)d_in[2];
    const float* kiso = (const float*)d_in[3];
    const float* norm = (const float*)d_in[4];

    float* C = (float*)d_out;                 // 256*256*192 floats
    float* ws = (float*)d_ws;
    const size_t IMG = (size_t)CN * HN * WN;  // 12,582,912
    const size_t PSQ = (size_t)CN * SN * SN;  // 16,777,216
    float* B   = ws;                          // IMG
    float* acc = ws + IMG;                    // IMG
    float* T   = ws + 2 * IMG;                // PSQ
    float* U   = T + PSQ;                     // PSQ

    const dim3 blk256(256);
    const dim3 convHGrid(WN / 64, HN / 64, CN);
    const dim3 convW192Grid(WN / 64, HN / 64, CN);
    const dim3 convW256Grid(SN / 64, HN / 64, CN);
    const dim3 rotFGrid(SN / 128, SN / 8, CN), rotBlk(32, 8);
    const dim3 rotBGrid(WN / 64, SN / 8, CN);

    // 1-2: gaussian separable conv -> C (d_out)
    conv_h_lds<<<convHGrid, blk256, 0, stream>>>(x, kg, B);
    conv_w_lds<WN, false><<<convW192Grid, blk256, 0, stream>>>(B, kg, C);
    // 3-4: iso separable conv -> acc
    conv_h_lds<<<convHGrid, blk256, 0, stream>>>(C, kiso, B);
    conv_w_lds<WN, false><<<convW192Grid, blk256, 0, stream>>>(B, kiso, acc);
    // 5: i=0 tail term (identity rotation): acc += conv_w(C, kw)
    conv_w_lds<WN, true><<<convW192Grid, blk256, 0, stream>>>(C, kw, acc);
    // 6-11: i=1,2 tail terms
    const double a1 = 60.0 * M_PI / 180.0, a2 = 120.0 * M_PI / 180.0;
    const float c1 = (float)cos(a1), s1 = (float)sin(a1);
    const float c2 = (float)cos(a2), s2 = (float)sin(a2);

    rot_fwd_k<<<rotFGrid, rotBlk, 0, stream>>>(C, T, c1, s1);
    conv_w_lds<SN, false><<<convW256Grid, blk256, 0, stream>>>(T, kw, U);
    rot_bwd_k<<<rotBGrid, rotBlk, 0, stream>>>(U, acc, c1, -s1);

    rot_fwd_k<<<rotFGrid, rotBlk, 0, stream>>>(C, T, c2, s2);
    conv_w_lds<SN, false><<<convW256Grid, blk256, 0, stream>>>(T, kw, U);
    rot_bwd_k<<<rotBGrid, rotBlk, 0, stream>>>(U, acc, c2, -s2);

    // 12: out = (C + acc) / norm[c]
    final_k<<<(unsigned)(IMG / 4 / 256), blk256, 0, stream>>>(C, acc, norm);
    (void)in_sizes; (void)n_in; (void)out_size; (void)ws_size;
}

// Round 5
// 1136.163 us; speedup vs baseline: 1.1666x; 1.1666x over previous
//
#include <hip/hip_runtime.h>
#include <cmath>

// Problem constants
#define CN   256   // channels (N_DIST)
#define HN   256   // H
#define WN   192   // W
#define KN   129   // kernel taps
#define RN   64    // radius
#define SN   256   // padded size
#define PADN 32    // (SN - WN)/2

// ================= conv along W (last axis), 4-stage LDS =================
// Block: 256 thr = 4 waves. Tile: 64 rows x 64 output cols; lane = row.
// Taps split into 4 stages of 32(33): stage s stages window offsets
// [32s, 32s+95] only -> LDS 64x97 words (24.8 KB, odd pitch: lane-strided
// b32 = 2 lanes/bank = conflict-free) -> 6 blocks/CU = 24 waves/CU.
template <int WD, bool ACC>
__global__ __launch_bounds__(256) void conv_w_lds(const float* __restrict__ in,
                                                  const float* __restrict__ kern,
                                                  float* __restrict__ out) {
    constexpr int PITCH = 97;
    __shared__ float lds[64 * PITCH + 132];
    float* __restrict__ ldsK = lds + 64 * PITCH;
    const int tid = threadIdx.x;
    const int x0  = blockIdx.x * 64;
    const int h0  = blockIdx.y * 64;
    const int c   = blockIdx.z;
    const float* __restrict__ in_c = in + ((size_t)c * HN + h0) * WD;

    if (tid < 132) ldsK[tid] = (tid < KN) ? kern[c * KN + tid] : 0.f;

    const int wv = tid >> 6;       // wave -> output col chunk
    const int l  = tid & 63;       // lane = row
    const int base = l * PITCH + wv * 16;  // element (u,t) = lds[base + u + t]

    float acc[16];
#pragma unroll
    for (int t = 0; t < 16; ++t) acc[t] = 0.f;

#pragma unroll 1
    for (int s = 0; s < 4; ++s) {
        __syncthreads();           // previous stage's reads done before restage
        // stage window offsets [32s, 32s+95]: global col x0 + 32s + col - 64
        for (int idx = tid; idx < 64 * 96; idx += 256) {
            int r = idx / 96, col = idx - r * 96;
            int g = x0 + 32 * s + col - 64;
            lds[r * PITCH + col] = (g >= 0 && g < WD) ? in_c[(size_t)r * WD + g] : 0.f;
        }
        __syncthreads();

        float w[16];
#pragma unroll
        for (int t = 0; t < 16; ++t) w[t] = lds[base + t];

#pragma unroll
        for (int u = 0; u < 32; ++u) {
            const float kj = ldsK[32 * s + u];
#pragma unroll
            for (int t = 0; t < 16; ++t)
                acc[t] = fmaf(w[(u + t) & 15], kj, acc[t]);
            w[u & 15] = lds[base + u + 16];   // max base offset 47 < 96
        }
        if (s == 3) {              // tap 128: slot t holds offset 32+t
            const float k128 = ldsK[128];
#pragma unroll
            for (int t = 0; t < 16; ++t)
                acc[t] = fmaf(w[t], k128, acc[t]);
        }
    }

    float4* __restrict__ o4 =
        (float4*)(out + ((size_t)c * HN + h0 + l) * WD + x0 + wv * 16);
#pragma unroll
    for (int q = 0; q < 4; ++q) {
        float4 v;
        v.x = acc[4*q]; v.y = acc[4*q+1]; v.z = acc[4*q+2]; v.w = acc[4*q+3];
        if (ACC) {
            float4 o = o4[q];
            v.x += o.x; v.y += o.y; v.z += o.z; v.w += o.w;
        }
        o4[q] = v;
    }
}

// ================= conv along H (axis 1), 4-stage LDS =================
// Block: 256 thr = 4 waves. Tile: 64 output rows x 64 cols; lane = col.
// Stage s stages rows [32s, 32s+95] x 64 cols (24.6 KB, row-major pitch 64,
// lane-consecutive = conflict-free).
__global__ __launch_bounds__(256) void conv_h_lds(const float* __restrict__ in,
                                                  const float* __restrict__ kern,
                                                  float* __restrict__ out) {
    __shared__ float lds[96 * 64 + 132];
    float* __restrict__ ldsK = lds + 96 * 64;
    const int tid = threadIdx.x;
    const int x0  = blockIdx.x * 64;
    const int h0  = blockIdx.y * 64;
    const int c   = blockIdx.z;
    const float* __restrict__ in_c = in + (size_t)c * HN * WN;

    if (tid < 132) ldsK[tid] = (tid < KN) ? kern[c * KN + tid] : 0.f;

    const int wv = tid >> 6;       // wave -> output row chunk
    const int l  = tid & 63;       // lane = col
    const int baseRow = wv * 16;   // element (u,t) = lds[(baseRow+u+t)*64 + l]

    float acc[16];
#pragma unroll
    for (int t = 0; t < 16; ++t) acc[t] = 0.f;

#pragma unroll 1
    for (int s = 0; s < 4; ++s) {
        __syncthreads();
        // stage rows [32s, 32s+95]: global row h0 + 32s + r - 64
        for (int idx = tid; idx < 96 * 64; idx += 256) {
            int r = idx >> 6, col = idx & 63;
            int g = h0 + 32 * s + r - 64;
            lds[r * 64 + col] = (g >= 0 && g < HN) ? in_c[(size_t)g * WN + x0 + col] : 0.f;
        }
        __syncthreads();

        float w[16];
#pragma unroll
        for (int t = 0; t < 16; ++t) w[t] = lds[(baseRow + t) * 64 + l];

#pragma unroll
        for (int u = 0; u < 32; ++u) {
            const float kj = ldsK[32 * s + u];
#pragma unroll
            for (int t = 0; t < 16; ++t)
                acc[t] = fmaf(w[(u + t) & 15], kj, acc[t]);
            w[u & 15] = lds[(baseRow + u + 16) * 64 + l];
        }
        if (s == 3) {
            const float k128 = ldsK[128];
#pragma unroll
            for (int t = 0; t < 16; ++t)
                acc[t] = fmaf(w[t], k128, acc[t]);
        }
    }

    float* __restrict__ ob = out + ((size_t)c * HN + h0 + wv * 16) * WN + x0 + l;
#pragma unroll
    for (int t = 0; t < 16; ++t) ob[(size_t)t * WN] = acc[t];
}

// ---------------- forward rotate of implicitly-padded C ----------------
// 4 outputs per thread along j (spaced 32) -> 16 gathers in flight.
__global__ __launch_bounds__(256) void rot_fwd_k(const float* __restrict__ Cin,
                                                 float* __restrict__ out,
                                                 float ca, float sa) {
    const int jb = blockIdx.x * 128 + threadIdx.x;  // + q*32
    const int i  = blockIdx.y * 8 + threadIdx.y;    // 0..255
    const int c  = blockIdx.z;
    const float cc = (SN - 1) * 0.5f;               // 127.5
    const float yy = (float)i - cc;
    const float* __restrict__ base = Cin + (size_t)c * HN * WN;
    float* __restrict__ orow = out + ((size_t)c * SN + i) * SN;
#pragma unroll
    for (int q = 0; q < 4; ++q) {
        const int j = jb + q * 32;
        float xx = (float)j - cc;
        float sy = ca * yy + sa * xx + cc;
        float sx = -sa * yy + ca * xx + cc;
        float y0f = floorf(sy), x0f = floorf(sx);
        float fy = sy - y0f, fx = sx - x0f;
        int y0 = (int)y0f, x0 = (int)x0f;
        auto g = [&](int yi, int xi) -> float {
            int p = xi - PADN;
            return (yi >= 0 && yi < SN && p >= 0 && p < WN)
                       ? base[(size_t)yi * WN + p] : 0.f;
        };
        float v = g(y0, x0) * (1.f - fy) * (1.f - fx)
                + g(y0, x0 + 1) * (1.f - fy) * fx
                + g(y0 + 1, x0) * fy * (1.f - fx)
                + g(y0 + 1, x0 + 1) * fy * fx;
        orow[j] = v;
    }
}

// ---------------- inverse rotate + accumulate into cropped acc -------------
// 2 outputs per thread along xc (spaced 32) -> 8 gathers in flight.
__global__ __launch_bounds__(256) void rot_bwd_k(const float* __restrict__ U,
                                                 float* __restrict__ acc,
                                                 float ca, float sa) {
    const int xb = blockIdx.x * 64 + threadIdx.x;  // + q*32
    const int i  = blockIdx.y * 8 + threadIdx.y;   // 0..255
    const int c  = blockIdx.z;
    const float cc = (SN - 1) * 0.5f;
    const float yy = (float)i - cc;
    const float* __restrict__ base = U + (size_t)c * SN * SN;
    float* __restrict__ arow = acc + ((size_t)c * HN + i) * WN;
#pragma unroll
    for (int q = 0; q < 2; ++q) {
        const int xc = xb + q * 32;
        const int j  = xc + PADN;
        float xx = (float)j - cc;
        float sy = ca * yy + sa * xx + cc;
        float sx = -sa * yy + ca * xx + cc;
        float y0f = floorf(sy), x0f = floorf(sx);
        float fy = sy - y0f, fx = sx - x0f;
        int y0 = (int)y0f, x0 = (int)x0f;
        auto g = [&](int yi, int xi) -> float {
            return (yi >= 0 && yi < SN && xi >= 0 && xi < SN)
                       ? base[(size_t)yi * SN + xi] : 0.f;
        };
        float v = g(y0, x0) * (1.f - fy) * (1.f - fx)
                + g(y0, x0 + 1) * (1.f - fy) * fx
                + g(y0 + 1, x0) * fy * (1.f - fx)
                + g(y0 + 1, x0 + 1) * fy * fx;
        arow[xc] += v;
    }
}

// ---------------- finalize: out = (C + acc) / norm[c], float4 ----------------
__global__ __launch_bounds__(256) void final_k(float* __restrict__ outC,
                                               const float* __restrict__ acc,
                                               const float* __restrict__ norm) {
    size_t i4 = (size_t)blockIdx.x * 256 + threadIdx.x;
    int c = (int)(i4 / (HN * WN / 4));
    float4* o4 = (float4*)outC;
    const float4* a4 = (const float4*)acc;
    float inv = 1.f / norm[c];
    float4 o = o4[i4], a = a4[i4];
    o.x = (o.x + a.x) * inv; o.y = (o.y + a.y) * inv;
    o.z = (o.z + a.z) * inv; o.w = (o.w + a.w) * inv;
    o4[i4] = o;
}

extern "C" void kernel_launch(void* const* d_in, const int* in_sizes, int n_in,
                              void* d_out, int out_size, void* d_ws, size_t ws_size,
                              hipStream_t stream) {
    const float* x    = (const float*)d_in[0];
    const float* kg   = (const float*)d_in[1];
    const float* kw   = (const float*)d_in[2];
    const float* kiso = (const float*)d_in[3];
    const float* norm = (const float*)d_in[4];

    float* C = (float*)d_out;                 // 256*256*192 floats
    float* ws = (float*)d_ws;
    const size_t IMG = (size_t)CN * HN * WN;  // 12,582,912
    const size_t PSQ = (size_t)CN * SN * SN;  // 16,777,216
    float* B   = ws;                          // IMG
    float* acc = ws + IMG;                    // IMG
    float* T   = ws + 2 * IMG;                // PSQ
    float* U   = T + PSQ;                     // PSQ

    const dim3 blk256(256);
    const dim3 convHGrid(WN / 64, HN / 64, CN);
    const dim3 convW192Grid(WN / 64, HN / 64, CN);
    const dim3 convW256Grid(SN / 64, HN / 64, CN);
    const dim3 rotFGrid(SN / 128, SN / 8, CN), rotBlk(32, 8);
    const dim3 rotBGrid(WN / 64, SN / 8, CN);

    // 1-2: gaussian separable conv -> C (d_out)
    conv_h_lds<<<convHGrid, blk256, 0, stream>>>(x, kg, B);
    conv_w_lds<WN, false><<<convW192Grid, blk256, 0, stream>>>(B, kg, C);
    // 3-4: iso separable conv -> acc
    conv_h_lds<<<convHGrid, blk256, 0, stream>>>(C, kiso, B);
    conv_w_lds<WN, false><<<convW192Grid, blk256, 0, stream>>>(B, kiso, acc);
    // 5: i=0 tail term (identity rotation): acc += conv_w(C, kw)
    conv_w_lds<WN, true><<<convW192Grid, blk256, 0, stream>>>(C, kw, acc);
    // 6-11: i=1,2 tail terms
    const double a1 = 60.0 * M_PI / 180.0, a2 = 120.0 * M_PI / 180.0;
    const float c1 = (float)cos(a1), s1 = (float)sin(a1);
    const float c2 = (float)cos(a2), s2 = (float)sin(a2);

    rot_fwd_k<<<rotFGrid, rotBlk, 0, stream>>>(C, T, c1, s1);
    conv_w_lds<SN, false><<<convW256Grid, blk256, 0, stream>>>(T, kw, U);
    rot_bwd_k<<<rotBGrid, rotBlk, 0, stream>>>(U, acc, c1, -s1);

    rot_fwd_k<<<rotFGrid, rotBlk, 0, stream>>>(C, T, c2, s2);
    conv_w_lds<SN, false><<<convW256Grid, blk256, 0, stream>>>(T, kw, U);
    rot_bwd_k<<<rotBGrid, rotBlk, 0, stream>>>(U, acc, c2, -s2);

    // 12: out = (C + acc) / norm[c]
    final_k<<<(unsigned)(IMG / 4 / 256), blk256, 0, stream>>>(C, acc, norm);
    (void)in_sizes; (void)n_in; (void)out_size; (void)ws_size;
}